// Round 2
// baseline (438.270 us; speedup 1.0000x reference)
//
#include <hip/hip_runtime.h>
#include <math.h>

#define EMB 1024
#define HID 1024
#define VOCAB 50257
#define HOUT_OFF VOCAB
#define COUT_OFF (VOCAB + 2*HID)
#define RPB 16                                   // rows per block (logits)
#define NB_LOGITS ((VOCAB + RPB - 1) / RPB)      // 3142

__device__ __forceinline__ float wave_reduce(float v) {
#pragma unroll
    for (int o = 32; o > 0; o >>= 1) v += __shfl_down(v, o);
    return v;
}

__device__ __forceinline__ float sigmoidf_(float x) { return 1.0f / (1.0f + expf(-x)); }

// One block per hidden unit r. Wave w (0..3) computes gate w (i/f/g/o):
//   gate = dot(W_ih[w*HID+r], x) + dot(W_hh[w*HID+r], h_prev) + b_ih + b_hh
// Thread 0 applies the LSTM cell and writes h,c to d_out (+ h to ws).
__global__ __launch_bounds__(256) void lstm_gemv(
    const float* __restrict__ Wih, const float* __restrict__ Whh,
    const float* __restrict__ bih, const float* __restrict__ bhh,
    const float* __restrict__ emb, const int* __restrict__ word,
    const float* __restrict__ x_in,            // null for layer 0 (use emb+relu)
    const float* __restrict__ h_prev, const float* __restrict__ c_prev,
    float* __restrict__ h_ws, float* __restrict__ out, int layer)
{
    const int r    = blockIdx.x;          // hidden unit 0..HID-1
    const int wave = threadIdx.x >> 6;    // 0..3 -> gate i/f/g/o
    const int lane = threadIdx.x & 63;
    const int row  = wave * HID + r;

    // 16 floats of x and h per lane (4 x float4), covering the 1024-dot.
    float4 xv[4], hv[4];
    if (x_in != nullptr) {
#pragma unroll
        for (int j = 0; j < 4; ++j) xv[j] = ((const float4*)x_in)[j*64 + lane];
    } else {
        const float4* e = (const float4*)(emb + (size_t)word[0] * EMB);
#pragma unroll
        for (int j = 0; j < 4; ++j) {
            float4 v = e[j*64 + lane];
            v.x = fmaxf(v.x, 0.f); v.y = fmaxf(v.y, 0.f);
            v.z = fmaxf(v.z, 0.f); v.w = fmaxf(v.w, 0.f);
            xv[j] = v;
        }
    }
#pragma unroll
    for (int j = 0; j < 4; ++j) hv[j] = ((const float4*)h_prev)[j*64 + lane];

    const float4* wih = (const float4*)(Wih + (size_t)row * EMB);
    const float4* whh = (const float4*)(Whh + (size_t)row * HID);
    float acc = 0.f;
#pragma unroll
    for (int j = 0; j < 4; ++j) {
        float4 a = wih[j*64 + lane];
        acc += a.x*xv[j].x + a.y*xv[j].y + a.z*xv[j].z + a.w*xv[j].w;
        float4 b = whh[j*64 + lane];
        acc += b.x*hv[j].x + b.y*hv[j].y + b.z*hv[j].z + b.w*hv[j].w;
    }
    acc = wave_reduce(acc);

    __shared__ float gates[4];
    if (lane == 0) gates[wave] = acc + bih[row] + bhh[row];
    __syncthreads();

    if (threadIdx.x == 0) {
        float ig = sigmoidf_(gates[0]);
        float fg = sigmoidf_(gates[1]);
        float gg = tanhf(gates[2]);
        float og = sigmoidf_(gates[3]);
        float c  = fg * c_prev[r] + ig * gg;
        float h  = og * tanhf(c);
        h_ws[r] = h;
        out[HOUT_OFF + layer * HID + r] = h;
        out[COUT_OFF + layer * HID + r] = c;
    }
}

// logits[row] = dot(W_out[row], h2) + b_out[row].
// Layout: 16 lanes per row, 4 rows per wave IN PARALLEL, 16 rows per block.
// Each lane issues 16 independent float4 loads (16 KB in flight per wave),
// then a 4-step shfl_xor reduce within its 16-lane group.
__global__ __launch_bounds__(256) void logits_gemv(
    const float* __restrict__ W, const float* __restrict__ b,
    const float* __restrict__ x, float* __restrict__ out,
    float* __restrict__ partials)
{
    const int tid = threadIdx.x;
    const int l   = tid & 15;                 // lane within 16-lane row group
    const int row = blockIdx.x * RPB + (tid >> 4);

    __shared__ float lg[RPB];
    if (tid < RPB) lg[tid] = -INFINITY;
    __syncthreads();

    float a0 = 0.f, a1 = 0.f, a2 = 0.f, a3 = 0.f;
    if (row < VOCAB) {
        const float4* __restrict__ wr = (const float4*)(W + (size_t)row * HID);
        const float4* __restrict__ xp = (const float4*)x;
#pragma unroll
        for (int j = 0; j < 4; ++j) {
            float4 w0 = wr[l + 16*(4*j+0)], x0 = xp[l + 16*(4*j+0)];
            float4 w1 = wr[l + 16*(4*j+1)], x1 = xp[l + 16*(4*j+1)];
            float4 w2 = wr[l + 16*(4*j+2)], x2 = xp[l + 16*(4*j+2)];
            float4 w3 = wr[l + 16*(4*j+3)], x3 = xp[l + 16*(4*j+3)];
            a0 += w0.x*x0.x + w0.y*x0.y + w0.z*x0.z + w0.w*x0.w;
            a1 += w1.x*x1.x + w1.y*x1.y + w1.z*x1.z + w1.w*x1.w;
            a2 += w2.x*x2.x + w2.y*x2.y + w2.z*x2.z + w2.w*x2.w;
            a3 += w3.x*x3.x + w3.y*x3.y + w3.z*x3.z + w3.w*x3.w;
        }
    }
    float acc = (a0 + a1) + (a2 + a3);
    acc += __shfl_xor(acc, 8);
    acc += __shfl_xor(acc, 4);
    acc += __shfl_xor(acc, 2);
    acc += __shfl_xor(acc, 1);

    if (l == 0 && row < VOCAB) {
        float logit = acc + b[row];
        out[row] = logit;
        lg[tid >> 4] = logit;
    }
    __syncthreads();

    if (tid == 0) {
        float M = -INFINITY, S = 0.f;
#pragma unroll
        for (int i = 0; i < RPB; ++i) {
            float v = lg[i];
            if (v > -INFINITY) {
                float nm = fmaxf(M, v);
                S = S * expf(M - nm) + expf(v - nm);
                M = nm;
            }
        }
        partials[2 * blockIdx.x]     = M;
        partials[2 * blockIdx.x + 1] = S;
    }
}

// Fused: every block redundantly folds the (L2-hot) per-block softmax
// partials into Z = M + log(S), then subtracts Z from its slice of logits.
__global__ __launch_bounds__(256) void logsoftmax_sub(
    float* __restrict__ out, const float* __restrict__ partials, int nb, int n)
{
    float M = -INFINITY, S = 0.f;
    for (int p = threadIdx.x; p < nb; p += 256) {
        float m = partials[2*p], s = partials[2*p + 1];
        float nm = fmaxf(M, m);
        S = S * expf(M - nm) + s * expf(m - nm);
        M = nm;
    }
    __shared__ float ms[256], ss[256];
    ms[threadIdx.x] = M; ss[threadIdx.x] = S;
    __syncthreads();
    for (int o = 128; o > 0; o >>= 1) {
        if (threadIdx.x < (unsigned)o) {
            float m2 = ms[threadIdx.x + o], s2 = ss[threadIdx.x + o];
            float m1 = ms[threadIdx.x];
            float nm = fmaxf(m1, m2);
            ss[threadIdx.x] = ss[threadIdx.x] * expf(m1 - nm) + s2 * expf(m2 - nm);
            ms[threadIdx.x] = nm;
        }
        __syncthreads();
    }
    float Z = ms[0] + logf(ss[0]);
    int i = blockIdx.x * 256 + threadIdx.x;
    if (i < n) out[i] -= Z;
}

extern "C" void kernel_launch(void* const* d_in, const int* in_sizes, int n_in,
                              void* d_out, int out_size, void* d_ws, size_t ws_size,
                              hipStream_t stream)
{
    const int*   word = (const int*)  d_in[0];
    const float* h0   = (const float*)d_in[1];
    const float* c0   = (const float*)d_in[2];
    const float* emb  = (const float*)d_in[3];
    const float* Wih0 = (const float*)d_in[4];
    const float* Whh0 = (const float*)d_in[5];
    const float* bih0 = (const float*)d_in[6];
    const float* bhh0 = (const float*)d_in[7];
    const float* Wih1 = (const float*)d_in[8];
    const float* Whh1 = (const float*)d_in[9];
    const float* bih1 = (const float*)d_in[10];
    const float* bhh1 = (const float*)d_in[11];
    const float* Wout = (const float*)d_in[12];
    const float* bout = (const float*)d_in[13];

    float* out = (float*)d_out;
    float* ws  = (float*)d_ws;
    float* h1       = ws;                      // HID floats
    float* h2       = ws + HID;                // HID floats
    float* partials = ws + 2 * HID;            // 2*NB_LOGITS floats

    lstm_gemv<<<HID, 256, 0, stream>>>(Wih0, Whh0, bih0, bhh0, emb, word,
                                       nullptr, h0, c0, h1, out, 0);
    lstm_gemv<<<HID, 256, 0, stream>>>(Wih1, Whh1, bih1, bhh1, emb, word,
                                       h1, h0 + HID, c0 + HID, h2, out, 1);
    logits_gemv<<<NB_LOGITS, 256, 0, stream>>>(Wout, bout, h2, out, partials);
    logsoftmax_sub<<<(VOCAB + 255) / 256, 256, 0, stream>>>(out, partials,
                                                            NB_LOGITS, VOCAB);
}